// Round 1
// baseline (484.386 us; speedup 1.0000x reference)
//
#include <hip/hip_runtime.h>

// Problem: 8192x8192 fp32 -> per-8x8-block DCT-II (orthonormal), per-block
// inf-norm `biggest`, int8 quantization indices = rint(coeff * 127/biggest).
// Output (flat fp32): [1024*1024*64 indices][1024*1024 biggest].
//
// One thread per 8x8 block. Memory-bound: ~520 MB traffic -> ~83 us floor.

#define IMG_H 8192
#define IMG_W 8192
#define NB1 (IMG_H / 8)
#define NB2 (IMG_W / 8)

__global__ __launch_bounds__(256) void dct_quant_kernel(
    const float* __restrict__ x,
    float* __restrict__ out_idx,   // NB1*NB2*64 floats (int8 values as fp32)
    float* __restrict__ out_big)   // NB1*NB2 floats
{
    // Orthonormal DCT-II matrix M[element][freq] for n=8, fp32-exact constants.
    // M[e][f] = 0.5*cos(pi*(2e+1)*f/16); M[e][0] = sqrt(1/8) == 0.5*cos(pi/4).
    constexpr float c1 = 0.4903926402016152f;
    constexpr float c2 = 0.4619397662556434f;
    constexpr float c3 = 0.4157348061512726f;
    constexpr float c4 = 0.35355339059327373f;
    constexpr float c5 = 0.2777851165098011f;
    constexpr float c6 = 0.1913417161825449f;
    constexpr float c7 = 0.0975451610080642f;
    constexpr float M[8][8] = {
        { c4,  c1,  c2,  c3,  c4,  c5,  c6,  c7},
        { c4,  c3,  c6, -c7, -c4, -c1, -c2, -c5},
        { c4,  c5, -c6, -c1, -c4,  c7,  c2,  c3},
        { c4,  c7, -c2, -c5,  c4,  c3, -c6, -c1},
        { c4, -c7, -c2,  c5,  c4, -c3, -c6,  c1},
        { c4, -c5, -c6,  c1, -c4, -c7,  c2, -c3},
        { c4, -c3,  c6,  c7, -c4,  c1, -c2,  c5},
        { c4, -c1,  c2, -c3,  c4, -c5,  c6, -c7},
    };

    const int tid = blockIdx.x * blockDim.x + threadIdx.x;
    const int b1 = tid >> 10;      // tid / NB2  (NB2 == 1024)
    const int b2 = tid & 1023;     // tid % NB2

    const float* src = x + (size_t)b1 * 8 * IMG_W + (size_t)b2 * 8;

    // Load the 8x8 block: 8 rows x 2 float4. Issue all loads up front so the
    // compiler can keep 16 global loads in flight per thread.
    float B[8][8];
#pragma unroll
    for (int e = 0; e < 8; ++e) {
        const float4* p = (const float4*)(src + (size_t)e * IMG_W);
        float4 lo = p[0];
        float4 hi = p[1];
        B[e][0] = lo.x; B[e][1] = lo.y; B[e][2] = lo.z; B[e][3] = lo.w;
        B[e][4] = hi.x; B[e][5] = hi.y; B[e][6] = hi.z; B[e][7] = hi.w;
    }

    // Stage 1 (row transform over f): T1[e][h] = sum_f B[e][f] * M[f][h].
    // In place per row -> no extra 64-reg array.
#pragma unroll
    for (int e = 0; e < 8; ++e) {
        float t[8];
#pragma unroll
        for (int h = 0; h < 8; ++h) {
            float s = B[e][0] * M[0][h];
#pragma unroll
            for (int f = 1; f < 8; ++f) s = fmaf(B[e][f], M[f][h], s);
            t[h] = s;
        }
#pragma unroll
        for (int h = 0; h < 8; ++h) B[e][h] = t[h];
    }

    // Stage 2 (column transform over e): C[g][h] = sum_e M[e][g] * T1[e][h].
    // In place per column; fuse the abs-max reduction.
    float big = 0.0f;
#pragma unroll
    for (int h = 0; h < 8; ++h) {
        float t[8];
#pragma unroll
        for (int g = 0; g < 8; ++g) {
            float s = M[0][g] * B[0][h];
#pragma unroll
            for (int e = 1; e < 8; ++e) s = fmaf(M[e][g], B[e][h], s);
            t[g] = s;
        }
#pragma unroll
        for (int g = 0; g < 8; ++g) {
            B[g][h] = t[g];
            big = fmaxf(big, fabsf(t[g]));
        }
    }

    // Quantize: jnp.round is round-half-to-even -> rintf matches.
    const float scale = 127.0f / big;
    float* o = out_idx + (size_t)tid * 64;
#pragma unroll
    for (int g = 0; g < 8; ++g) {
        float4 v0, v1;
        v0.x = rintf(B[g][0] * scale);
        v0.y = rintf(B[g][1] * scale);
        v0.z = rintf(B[g][2] * scale);
        v0.w = rintf(B[g][3] * scale);
        v1.x = rintf(B[g][4] * scale);
        v1.y = rintf(B[g][5] * scale);
        v1.z = rintf(B[g][6] * scale);
        v1.w = rintf(B[g][7] * scale);
        ((float4*)o)[2 * g]     = v0;
        ((float4*)o)[2 * g + 1] = v1;
    }
    out_big[tid] = big;
}

extern "C" void kernel_launch(void* const* d_in, const int* in_sizes, int n_in,
                              void* d_out, int out_size, void* d_ws, size_t ws_size,
                              hipStream_t stream) {
    const float* x = (const float*)d_in[0];
    // d_in[1] is the dct matrix; it's a fixed function of BLOCK=8 and is
    // hardcoded (fp32-identical) in the kernel.
    float* out = (float*)d_out;
    float* out_idx = out;                                // (NB1,NB2,64)
    float* out_big = out + (size_t)NB1 * NB2 * 64;       // (NB1,NB2)

    const int nthreads = NB1 * NB2;   // one thread per 8x8 block
    dct_quant_kernel<<<nthreads / 256, 256, 0, stream>>>(x, out_idx, out_big);
}

// Round 2
// 469.991 us; speedup vs baseline: 1.0306x; 1.0306x over previous
//
#include <hip/hip_runtime.h>

// Problem: 8192x8192 fp32 -> per-8x8-block DCT-II (orthonormal), per-block
// inf-norm `biggest`, int8 quantization indices = rint(coeff * 127/biggest).
// Output (flat fp32): [1024*1024*64 indices][1024*1024 biggest].
//
// One thread per 8x8 block. Memory-bound: ~540 MB HBM traffic -> ~86 us floor.
//
// R1 note: R0 compiled to 44 VGPRs -> the 64-float live set spilled to
// scratch (WRITE_SIZE showed +62 MB of spill traffic). __launch_bounds__
// (256, 4) = 4 waves/EU min -> 128-VGPR cap, enough to hold the block.

#define IMG_H 8192
#define IMG_W 8192
#define NB1 (IMG_H / 8)
#define NB2 (IMG_W / 8)

__global__ __launch_bounds__(256, 4) void dct_quant_kernel(
    const float* __restrict__ x,
    float* __restrict__ out_idx,   // NB1*NB2*64 floats (int8 values as fp32)
    float* __restrict__ out_big)   // NB1*NB2 floats
{
    // Orthonormal DCT-II matrix M[element][freq] for n=8, fp32-exact constants.
    // M[e][f] = 0.5*cos(pi*(2e+1)*f/16); M[e][0] = sqrt(1/8) == 0.5*cos(pi/4).
    constexpr float c1 = 0.4903926402016152f;
    constexpr float c2 = 0.4619397662556434f;
    constexpr float c3 = 0.4157348061512726f;
    constexpr float c4 = 0.35355339059327373f;
    constexpr float c5 = 0.2777851165098011f;
    constexpr float c6 = 0.1913417161825449f;
    constexpr float c7 = 0.0975451610080642f;
    constexpr float M[8][8] = {
        { c4,  c1,  c2,  c3,  c4,  c5,  c6,  c7},
        { c4,  c3,  c6, -c7, -c4, -c1, -c2, -c5},
        { c4,  c5, -c6, -c1, -c4,  c7,  c2,  c3},
        { c4,  c7, -c2, -c5,  c4,  c3, -c6, -c1},
        { c4, -c7, -c2,  c5,  c4, -c3, -c6,  c1},
        { c4, -c5, -c6,  c1, -c4, -c7,  c2, -c3},
        { c4, -c3,  c6,  c7, -c4,  c1, -c2,  c5},
        { c4, -c1,  c2, -c3,  c4, -c5,  c6, -c7},
    };

    const int tid = blockIdx.x * blockDim.x + threadIdx.x;
    const int b1 = tid >> 10;      // tid / NB2  (NB2 == 1024)
    const int b2 = tid & 1023;     // tid % NB2

    const float* src = x + (size_t)b1 * 8 * IMG_W + (size_t)b2 * 8;

    // Load the 8x8 block: 8 rows x 2 float4, all issued up front.
    float B[8][8];
#pragma unroll
    for (int e = 0; e < 8; ++e) {
        const float4* p = (const float4*)(src + (size_t)e * IMG_W);
        float4 lo = p[0];
        float4 hi = p[1];
        B[e][0] = lo.x; B[e][1] = lo.y; B[e][2] = lo.z; B[e][3] = lo.w;
        B[e][4] = hi.x; B[e][5] = hi.y; B[e][6] = hi.z; B[e][7] = hi.w;
    }

    // Stage 1 (row transform over f): T1[e][h] = sum_f B[e][f] * M[f][h].
#pragma unroll
    for (int e = 0; e < 8; ++e) {
        float t[8];
#pragma unroll
        for (int h = 0; h < 8; ++h) {
            float s = B[e][0] * M[0][h];
#pragma unroll
            for (int f = 1; f < 8; ++f) s = fmaf(B[e][f], M[f][h], s);
            t[h] = s;
        }
#pragma unroll
        for (int h = 0; h < 8; ++h) B[e][h] = t[h];
    }

    // Stage 2 (column transform over e): C[g][h] = sum_e M[e][g] * T1[e][h].
    // Fused abs-max reduction.
    float big = 0.0f;
#pragma unroll
    for (int h = 0; h < 8; ++h) {
        float t[8];
#pragma unroll
        for (int g = 0; g < 8; ++g) {
            float s = M[0][g] * B[0][h];
#pragma unroll
            for (int e = 1; e < 8; ++e) s = fmaf(M[e][g], B[e][h], s);
            t[g] = s;
        }
#pragma unroll
        for (int g = 0; g < 8; ++g) {
            B[g][h] = t[g];
            big = fmaxf(big, fabsf(t[g]));
        }
    }

    // Quantize: jnp.round is round-half-to-even -> rintf matches.
    const float scale = 127.0f / big;
    float* o = out_idx + (size_t)tid * 64;
#pragma unroll
    for (int g = 0; g < 8; ++g) {
        float4 v0, v1;
        v0.x = rintf(B[g][0] * scale);
        v0.y = rintf(B[g][1] * scale);
        v0.z = rintf(B[g][2] * scale);
        v0.w = rintf(B[g][3] * scale);
        v1.x = rintf(B[g][4] * scale);
        v1.y = rintf(B[g][5] * scale);
        v1.z = rintf(B[g][6] * scale);
        v1.w = rintf(B[g][7] * scale);
        ((float4*)o)[2 * g]     = v0;
        ((float4*)o)[2 * g + 1] = v1;
    }
    out_big[tid] = big;
}

extern "C" void kernel_launch(void* const* d_in, const int* in_sizes, int n_in,
                              void* d_out, int out_size, void* d_ws, size_t ws_size,
                              hipStream_t stream) {
    const float* x = (const float*)d_in[0];
    // d_in[1] is the dct matrix; fixed function of BLOCK=8, hardcoded
    // (fp32-identical) in the kernel.
    float* out = (float*)d_out;
    float* out_idx = out;                                // (NB1,NB2,64)
    float* out_big = out + (size_t)NB1 * NB2 * 64;       // (NB1,NB2)

    const int nthreads = NB1 * NB2;   // one thread per 8x8 block
    dct_quant_kernel<<<nthreads / 256, 256, 0, stream>>>(x, out_idx, out_big);
}